// Round 6
// baseline (99.583 us; speedup 1.0000x reference)
//
#include <hip/hip_runtime.h>

typedef float f32x2 __attribute__((ext_vector_type(2)));

constexpr int BLOCK = 256;
constexpr int IPT   = 2;   // anchors per thread, packed as one f32x2 lane-pair
constexpr int BPB   = 8;   // all batches per block -> 512 identical-work blocks, 2/CU

__global__ __launch_bounds__(BLOCK, 2) void assign_cls_label_kernel(
    const float* __restrict__ anchorss,    // (B,N,4) y,x,h,w (or y1,x1,y2,x2)
    const float4* __restrict__ gt_boxes4,  // (B,A) of float4 (y1,x1,y2,x2)
    const int* __restrict__ gt_counts,     // (B,1)
    const int* __restrict__ use_anchor_p,  // scalar
    int* __restrict__ out,                 // (B,N)
    int N, int A, int B)
{
#pragma clang fp contract(off)
    const int tid = threadIdx.x;
    const int b0  = blockIdx.y * BPB;

    const int n0r = blockIdx.x * (BLOCK * IPT) + tid;   // lane-contiguous -> coalesced
    const int n1r = n0r + BLOCK;
    const int n0  = (n0r < N) ? n0r : N - 1;            // tail clamp (stores guarded)
    const int n1  = (n1r < N) ? n1r : N - 1;

    // rolling anchor prefetch (VMEM), batch 0 first
    float4 an0 = ((const float4*)anchorss)[(size_t)b0 * N + n0];
    float4 an1 = ((const float4*)anchorss)[(size_t)b0 * N + n1];

    const int   use_anchor = use_anchor_p[0];
    const float c26 = 1.0f / 67108864.0f;  // fl(i/u)>=0.5 <=> i-(0.5-2^-26)u >= 0 (sign-exact)
    const int   Am1 = A - 1;

#pragma clang loop unroll(disable)
    for (int bb = 0; bb < BPB; ++bb) {
        if (b0 + bb >= B) break;                        // uniform
        // block-uniform address stream -> scalar (SMEM) loads, no LDS, no syncthreads
        const int count = gt_counts[b0 + bb];
        const float4* __restrict__ grow = gt_boxes4 + (size_t)(b0 + bb) * A;

        const float4 ac0 = an0, ac1 = an1;
        if (bb + 1 < BPB && b0 + bb + 1 < B) {          // prefetch next batch's anchors
            const float4* arow = (const float4*)anchorss + (size_t)(b0 + bb + 1) * N;
            an0 = arow[n0];
            an1 = arow[n1];
        }

        f32x2 Y1, X1, Y2, X2, AREA;
        if (use_anchor) {
            const f32x2 H  = {ac0.z, ac1.z};
            const f32x2 W  = {ac0.w, ac1.w};
            const f32x2 Yc = {ac0.x, ac1.x};
            const f32x2 Xc = {ac0.y, ac1.y};
            Y1 = Yc - H * 0.5f;    // h*0.5 exact; one rounded sub == ref's y - h/2
            Y2 = Y1 + H;
            X1 = Xc - W * 0.5f;
            X2 = X1 + W;
            AREA = H * W;
        } else {
            Y1 = f32x2{ac0.x, ac1.x}; X1 = f32x2{ac0.y, ac1.y};
            Y2 = f32x2{ac0.z, ac1.z}; X2 = f32x2{ac0.w, ac1.w};
            AREA = (Y2 - Y1) * (X2 - X1);
        }
        f32x2 ACC = {-1.0f, -1.0f};

        auto comp = [&](const float4 g) {
            const float ga = (g.z - g.x) * (g.w - g.y);   // ref op order
            f32x2 yy1, yy2, xx1, xx2;
            yy1.x = __builtin_amdgcn_fmed3f(Y1.x, g.x, g.z);
            yy1.y = __builtin_amdgcn_fmed3f(Y1.y, g.x, g.z);
            yy2.x = __builtin_amdgcn_fmed3f(Y2.x, g.x, g.z);
            yy2.y = __builtin_amdgcn_fmed3f(Y2.y, g.x, g.z);
            xx1.x = __builtin_amdgcn_fmed3f(X1.x, g.y, g.w);
            xx1.y = __builtin_amdgcn_fmed3f(X1.y, g.y, g.w);
            xx2.x = __builtin_amdgcn_fmed3f(X2.x, g.y, g.w);
            xx2.y = __builtin_amdgcn_fmed3f(X2.y, g.y, g.w);
            const f32x2 dy    = yy2 - yy1;
            const f32x2 dx    = xx2 - xx1;
            const f32x2 inter = dy * dx;
            const f32x2 u     = (AREA + ga) - inter;      // ref assoc: (area+ga)-inter
            const f32x2 mh    = {-0.5f, -0.5f};
            const f32x2 cc    = {c26, c26};
            const f32x2 e = __builtin_elementwise_fma(u, mh, inter); // Sterbenz-exact band
            const f32x2 r = __builtin_elementwise_fma(u, cc, e);     // sign-exact decision
            ACC = __builtin_elementwise_max(ACC, r);
        };

        // 2-bank x 4-deep software pipeline in SGPRs; clamps are uniform SALU s_min
        float4 g0, g1, g2, g3, h0, h1, h2, h3;
        g0 = grow[0];
        g1 = grow[min(1, Am1)];
        g2 = grow[min(2, Am1)];
        g3 = grow[min(3, Am1)];
        int gi = 0;
        while (gi + 8 <= count) {
            h0 = grow[gi + 4]; h1 = grow[gi + 5];        // gi+7 <= count-1 <= A-1: in-bounds
            h2 = grow[gi + 6]; h3 = grow[gi + 7];
            comp(g0); comp(g1); comp(g2); comp(g3);
            g0 = grow[min(gi + 8,  Am1)]; g1 = grow[min(gi + 9,  Am1)];
            g2 = grow[min(gi + 10, Am1)]; g3 = grow[min(gi + 11, Am1)];
            comp(h0); comp(h1); comp(h2); comp(h3);
            gi += 8;
        }
        const int rem = count - gi;                      // 0..7; bank g holds gi..gi+3
        if (rem > 4) {
            h0 = grow[min(gi + 4, Am1)]; h1 = grow[min(gi + 5, Am1)];
            h2 = grow[min(gi + 6, Am1)]; h3 = grow[min(gi + 7, Am1)];
        }
        if (rem > 0) comp(g0);
        if (rem > 1) comp(g1);
        if (rem > 2) comp(g2);
        if (rem > 3) comp(g3);
        if (rem > 4) comp(h0);
        if (rem > 5) comp(h1);
        if (rem > 6) comp(h2);

        int* orow = out + (size_t)(b0 + bb) * N;
        if (n0r < N) orow[n0r] = (ACC.x >= 0.0f) ? 1 : 0;
        if (n1r < N) orow[n1r] = (ACC.y >= 0.0f) ? 1 : 0;
    }
}

extern "C" void kernel_launch(void* const* d_in, const int* in_sizes, int n_in,
                              void* d_out, int out_size, void* d_ws, size_t ws_size,
                              hipStream_t stream) {
    const float*  anchorss   = (const float*)d_in[0];
    const float4* gt_boxes4  = (const float4*)d_in[1];
    const int*    gt_counts  = (const int*)d_in[2];
    const int*    use_anchor = (const int*)d_in[3];
    int*          out        = (int*)d_out;

    const int B = in_sizes[2];              // gt_counts is (B,1)
    const int A = in_sizes[1] / (4 * B);    // gt_bboxess is (B,A,4)
    const int N = in_sizes[0] / (4 * B);    // anchorss   is (B,N,4)

    dim3 grid((N + BLOCK * IPT - 1) / (BLOCK * IPT), (B + BPB - 1) / BPB);
    hipLaunchKernelGGL(assign_cls_label_kernel, grid, dim3(BLOCK), 0, stream,
                       anchorss, gt_boxes4, gt_counts, use_anchor, out, N, A, B);
}